// Round 1
// baseline (18.217 us; speedup 1.0000x reference)
//
#include <hip/hip_runtime.h>
#include <hip/hip_bf16.h>

// Hierarchical softmax:
//   out[n] = prod_{d < path_len[id[n]]} sigmoid( W[paths[id[n]][d]] . x + b[...] )
//
// Key transform: x is a SINGLE vector shared by all targets, so precompute
//   s[node] = sigmoid(W[node].x + b[node])  for all N_NODES nodes (one pass
// over W = 51.2 MB), then each target is just 24 gathers from a 400 KB table.

#define EMBED 128
#define MAX_DEPTH 24

// ---------------- Kernel 1: per-node sigmoid(W.x + b) -> s table ------------
// 16 lanes per node; each lane loads 2x float4 (8 floats) of the row.
__global__ __launch_bounds__(256) void hs_node_sigmoid(
    const float* __restrict__ x, const float* __restrict__ W,
    const float* __restrict__ b, float* __restrict__ s, int n_nodes) {
  int tid = blockIdx.x * blockDim.x + threadIdx.x;
  int node = tid >> 4;
  int sub = tid & 15;
  if (node >= n_nodes) return;

  const float4* xr = (const float4*)x;
  const float4* wr = (const float4*)(W + (size_t)node * EMBED);
  float4 xa = xr[sub];        // elements sub*4 .. sub*4+3
  float4 xb = xr[16 + sub];   // elements 64+sub*4 ..
  float4 wa = wr[sub];
  float4 wb = wr[16 + sub];

  float p = wa.x * xa.x + wa.y * xa.y + wa.z * xa.z + wa.w * xa.w +
            wb.x * xb.x + wb.y * xb.y + wb.z * xb.z + wb.w * xb.w;
#pragma unroll
  for (int m = 1; m < 16; m <<= 1) p += __shfl_xor(p, m);

  if (sub == 0) {
    float logit = p + b[node];
    s[node] = 1.0f / (1.0f + __expf(-logit));
  }
}

// ---------------- Kernel 2: per-target path product -------------------------
// 32 lanes per target: lane d gathers s[paths[id][d]] (1.0 if masked),
// then a 5-step shfl_xor multiply-reduce.
__global__ __launch_bounds__(256) void hs_gather_prod(
    const int* __restrict__ id_list, const int* __restrict__ paths,
    const int* __restrict__ path_len, const float* __restrict__ s,
    float* __restrict__ out, int batch) {
  int tid = blockIdx.x * blockDim.x + threadIdx.x;
  int t = tid >> 5;
  int lane = tid & 31;
  if (t >= batch) return;

  int id = id_list[t];
  int len = path_len[id];
  float p = 1.0f;
  if (lane < MAX_DEPTH) {
    int node = paths[id * MAX_DEPTH + lane];  // lanes 0..23 read consecutive ints
    if (lane < len) p = s[node];              // 400 KB table: L2-resident
  }
#pragma unroll
  for (int m = 1; m < 32; m <<= 1) p *= __shfl_xor(p, m);
  if (lane == 0) out[t] = p;
}

// ---------------- Fallback: fused per-target kernel (if ws too small) -------
// One 64-lane wave per target; 4 groups of 16 lanes each handle one depth
// per iteration (6 iterations cover 24 depths).
__global__ __launch_bounds__(256) void hs_fused(
    const float* __restrict__ x, const int* __restrict__ id_list,
    const float* __restrict__ W, const float* __restrict__ b,
    const int* __restrict__ paths, const int* __restrict__ path_len,
    float* __restrict__ out, int batch) {
  int tid = blockIdx.x * blockDim.x + threadIdx.x;
  int t = tid >> 6;
  int lane = threadIdx.x & 63;
  int g = lane >> 4, sub = lane & 15;
  if (t >= batch) return;

  int id = id_list[t];
  int len = path_len[id];
  const float4* xr = (const float4*)x;
  float4 xa = xr[sub];
  float4 xb = xr[16 + sub];

  float prod = 1.0f;
#pragma unroll
  for (int it = 0; it < MAX_DEPTH / 4; ++it) {
    int d = it * 4 + g;
    int node = paths[id * MAX_DEPTH + d];
    const float4* wr = (const float4*)(W + (size_t)node * EMBED);
    float4 wa = wr[sub], wb = wr[16 + sub];
    float p = wa.x * xa.x + wa.y * xa.y + wa.z * xa.z + wa.w * xa.w +
              wb.x * xb.x + wb.y * xb.y + wb.z * xb.z + wb.w * xb.w;
#pragma unroll
    for (int m = 1; m < 16; m <<= 1) p += __shfl_xor(p, m);
    float sig = 1.0f / (1.0f + __expf(-(p + b[node])));
    prod *= (d < len) ? sig : 1.0f;
  }
  prod *= __shfl_xor(prod, 16);
  prod *= __shfl_xor(prod, 32);
  if (lane == 0) out[t] = prod;
}

extern "C" void kernel_launch(void* const* d_in, const int* in_sizes, int n_in,
                              void* d_out, int out_size, void* d_ws, size_t ws_size,
                              hipStream_t stream) {
  const float* x        = (const float*)d_in[0];  // [1,128]
  const int*   id_list  = (const int*)d_in[1];    // [16384]
  const float* W        = (const float*)d_in[2];  // [99999,128]
  const float* b        = (const float*)d_in[3];  // [99999]
  const int*   paths    = (const int*)d_in[4];    // [100000,24]
  const int*   path_len = (const int*)d_in[5];    // [100000]
  float* out = (float*)d_out;

  int n_nodes = in_sizes[3];
  int batch   = in_sizes[1];

  if (ws_size >= (size_t)n_nodes * sizeof(float)) {
    float* s = (float*)d_ws;
    int threads1 = n_nodes * 16;
    hs_node_sigmoid<<<(threads1 + 255) / 256, 256, 0, stream>>>(x, W, b, s, n_nodes);
    int threads2 = batch * 32;
    hs_gather_prod<<<(threads2 + 255) / 256, 256, 0, stream>>>(id_list, paths, path_len, s, out, batch);
  } else {
    int threads = batch * 64;
    hs_fused<<<(threads + 255) / 256, 256, 0, stream>>>(x, id_list, W, b, paths, path_len, out, batch);
  }
}